// Round 21
// baseline (1337.900 us; speedup 1.0000x reference)
//
#include <hip/hip_runtime.h>
#include <hip/hip_bf16.h>
#include <math.h>

// AoA Reader v16: v15 + raw barrier in GRU (lgkmcnt-only wait, NO sched_barrier,
// no vmcnt drain per step). Single isolated change vs r20.
// V=50000 E=384 H=256 B=32 D=1024 Q=64 C=10.
#define BATCH 32
#define DLEN 1024
#define QLEN 64
#define EMB 384
#define HID 256
#define G3 768   // 3*H
#define NCAND 10
#define VOCAB 50000

typedef __attribute__((ext_vector_type(8))) short bf16x8;
typedef __attribute__((ext_vector_type(8))) unsigned short u16x8;
typedef __attribute__((ext_vector_type(4))) float f32x4;
#define MFMA16 __builtin_amdgcn_mfma_f32_16x16x32_bf16

__device__ __forceinline__ float bf2f(ushort u) {
    union { float f; unsigned v; } x; x.v = ((unsigned)u) << 16; return x.f;
}
__device__ __forceinline__ ushort f2bf(float f) {
    union { float f; unsigned v; } x; x.f = f;
    unsigned r = x.v + 0x7FFF + ((x.v >> 16) & 1);
    return (ushort)(r >> 16);
}
__device__ __forceinline__ float sigf(float x) {
    return __builtin_amdgcn_rcpf(1.f + __expf(-x));
}
__device__ __forceinline__ float tanhf_(float x) {
    return 1.f - 2.f * __builtin_amdgcn_rcpf(1.f + __expf(2.f * x));
}
__device__ __forceinline__ bf16x8 cvt8(float4 a, float4 b) {
    union { unsigned u[4]; bf16x8 v; } r;
    asm("v_cvt_pk_bf16_f32 %0, %1, %2" : "=v"(r.u[0]) : "v"(a.x), "v"(a.y));
    asm("v_cvt_pk_bf16_f32 %0, %1, %2" : "=v"(r.u[1]) : "v"(a.z), "v"(a.w));
    asm("v_cvt_pk_bf16_f32 %0, %1, %2" : "=v"(r.u[2]) : "v"(b.x), "v"(b.y));
    asm("v_cvt_pk_bf16_f32 %0, %1, %2" : "=v"(r.u[3]) : "v"(b.z), "v"(b.w));
    return r.v;
}

// ---------------- fused prep: embB + wihB(f,b) + bias_eff + wprep in ONE launch ----------------
#define NE8 (VOCAB * EMB / 8)
#define NW8 (G3 * EMB / 8)
__global__ __launch_bounds__(256) void k_prep_all(
    const float* __restrict__ emb, const float* __restrict__ wihf, const float* __restrict__ wihb,
    const float* __restrict__ bihf, const float* __restrict__ bhhf,
    const float* __restrict__ bihb, const float* __restrict__ bhhb,
    const float* __restrict__ whf, const float* __restrict__ whb,
    ushort* __restrict__ embB, ushort* __restrict__ wihB,
    float* __restrict__ be, ushort* __restrict__ wprep)
{
    long i = (long)blockIdx.x * 256 + threadIdx.x;
    if (i < NE8) {
        const float* p = emb + i * 8;
        *(bf16x8*)(embB + i * 8) = cvt8(*(const float4*)p, *(const float4*)(p + 4));
        return;
    }
    i -= NE8;
    if (i < 2 * NW8) {
        const float* w = (i < NW8) ? wihf : wihb;
        long c = (i < NW8) ? i : i - NW8;
        const float* p = w + c * 8;
        *(bf16x8*)(wihB + i * 8) = cvt8(*(const float4*)p, *(const float4*)(p + 4));
        return;
    }
    i -= 2 * NW8;
    if (i < 1536) {
        int dir = (int)i / G3, c = (int)i - dir * G3;
        const float* bih = dir ? bihb : bihf;
        const float* bhh = dir ? bhhb : bhhf;
        be[i] = bih[c] + (c < 512 ? bhh[c] : 0.f);
        return;
    }
    i -= 1536;
    if (i < 393216) {
        int idx = (int)i;
        int dir = idx / 196608;
        int r = idx - dir * 196608;
        int wv = r / 24576;  int r2 = r - wv * 24576;
        int tile = r2 / 4096; int r3 = r2 - tile * 4096;
        int ks = r3 / 512;    int r4 = r3 - ks * 512;
        int lane = r4 >> 3;   int e = r4 & 7;
        int g = (tile >> 1) * 256 + wv * 32 + (tile & 1) * 16 + (lane & 15);
        int k = ks * 32 + (lane >> 4) * 8 + e;
        const float* w = dir ? whb : whf;
        wprep[idx] = f2bf(w[g * 256 + k]);
    }
}
#define PREP_TOTAL ((long)NE8 + 2 * NW8 + 1536 + 393216)

// ---------------- gx GEMM with gather, MFMA bf16 (all-bf16, natural coalesced out) ----------------
__global__ __launch_bounds__(256) void k_gx(const int* __restrict__ tokens,
                                            const ushort* __restrict__ embB,
                                            const ushort* __restrict__ wih0, const float* __restrict__ bias0, ushort* __restrict__ out0,
                                            const ushort* __restrict__ wih1, const float* __restrict__ bias1, ushort* __restrict__ out1) {
    __shared__ ushort Asl[64][392];              // 384 k + 8 pad, 50 KB
    const ushort* wih = blockIdx.z ? wih1 : wih0;
    const float* bia  = blockIdx.z ? bias1 : bias0;
    ushort* out       = blockIdx.z ? out1 : out0;
    int tid = threadIdx.x;
    int n0 = blockIdx.x * 64;
    long m0 = (long)blockIdx.y * 64;
    int wv = tid >> 6;
    int lane = tid & 63;
    int l15 = lane & 15;
    int lhi = lane >> 4;

    // ---- stage A: 4 threads/row, 12 x 16B bf16 loads each ----
    {
        int row = tid >> 2, kq = tid & 3;
        long tok = tokens[m0 + row];
        const ushort* ar = embB + tok * EMB + kq * 96;
#pragma unroll
        for (int it = 0; it < 12; ++it)
            *(u16x8*)&Asl[row][kq * 96 + it * 8] = *(const u16x8*)(ar + it * 8);
    }
    __syncthreads();

    // ---- compute: wave wv = n-tile; 4 m-subtiles ----
    int n = n0 + wv * 16 + l15;
    const ushort* brow = wih + (long)n * EMB;
    f32x4 acc[4] = {};
#pragma unroll
    for (int ks = 0; ks < 12; ++ks) {
        bf16x8 bf = *(const bf16x8*)(brow + ks * 32 + lhi * 8);
#pragma unroll
        for (int mt = 0; mt < 4; ++mt) {
            bf16x8 a = *(const bf16x8*)&Asl[mt * 16 + l15][ks * 32 + lhi * 8];
            acc[mt] = MFMA16(a, bf, acc[mt], 0, 0, 0);
        }
    }

    // ---- epilogue: bias + natural bf16 store (16 lanes -> 32B contiguous) ----
    float bias = bia[n];
#pragma unroll
    for (int mt = 0; mt < 4; ++mt)
#pragma unroll
        for (int r = 0; r < 4; ++r) {
            long m = m0 + mt * 16 + lhi * 4 + r;
            out[m * G3 + n] = f2bf(acc[mt][r] + bias);
        }
}

// ---------------- MFMA GRU: grid 64 = (bgroup(16), dir(2), seq(2)). 512 thr = 8 waves. ----------------
// nb=2; batch bi -> A-row bi*4 (row-alias A-read). All 6 B-tiles in registers.
// setprio around MFMA. RAW barrier (lgkmcnt-only; no per-step vmcnt drain).
__global__ __attribute__((amdgpu_flat_work_group_size(512, 512), amdgpu_waves_per_eu(2, 2)))
void k_gru5(
    const ushort* __restrict__ gxd_f, const ushort* __restrict__ gxd_b,
    const ushort* __restrict__ gxq_f, const ushort* __restrict__ gxq_b,
    const ushort* __restrict__ wprep,
    const float* __restrict__ bhh_f, const float* __restrict__ bhh_b,
    const int* __restrict__ dlens, const int* __restrict__ qlens,
    ushort* __restrict__ dosb, ushort* __restrict__ qosb)
{
    int wg = blockIdx.x;
    int bgroup = wg & 15;
    int dir = (wg >> 4) & 1;
    int seq = wg >> 5;                   // 0=doc, 1=query
    int T = seq ? QLEN : DLEN;
    const ushort* gx = seq ? (dir ? gxq_b : gxq_f) : (dir ? gxd_b : gxd_f);
    const float* bhh = dir ? bhh_b : bhh_f;
    const int* lens = seq ? qlens : dlens;
    ushort* outbase = (seq ? qosb : dosb) + dir * HID;
    int boff = bgroup * 2;

    int tid = threadIdx.x;
    int wv = tid >> 6;
    int lane = tid & 63;
    int l15 = lane & 15;
    int lhi = lane >> 4;
    int bi = lhi & 1;                    // local batch
    int p  = lhi >> 1;                   // j-half
    int jw = wv * 32;

    __shared__ ushort hbuf[2][2048];     // 8 KB bf16 h (8 rows), swizzled, dbuf

    // ---- resident weights: ALL 6 tiles in registers ----
    const ushort* wp = wprep + (size_t)dir * 196608;
    bf16x8 B0[8], B1[8], B2[8], B3[8], B4[8], B5[8];
#pragma unroll
    for (int ks = 0; ks < 8; ++ks) {
        B0[ks] = *(const bf16x8*)(wp + ((((wv * 6 + 0) * 8 + ks) * 64 + lane) * 8));
        B1[ks] = *(const bf16x8*)(wp + ((((wv * 6 + 1) * 8 + ks) * 64 + lane) * 8));
        B2[ks] = *(const bf16x8*)(wp + ((((wv * 6 + 2) * 8 + ks) * 64 + lane) * 8));
        B3[ks] = *(const bf16x8*)(wp + ((((wv * 6 + 3) * 8 + ks) * 64 + lane) * 8));
        B4[ks] = *(const bf16x8*)(wp + ((((wv * 6 + 4) * 8 + ks) * 64 + lane) * 8));
        B5[ks] = *(const bf16x8*)(wp + ((((wv * 6 + 5) * 8 + ks) * 64 + lane) * 8));
    }

    float bhn0 = bhh[512 + jw + l15];
    float bhn1 = bhh[512 + jw + 16 + l15];
    int len = lens[boff + bi];
    float hp = 0.f;
    ushort hbf = 0;

    // ---- precomputed static addresses (t-invariant) ----
    int rl = l15 & 7;                    // aliased A-row (8..15 -> 0..7, same data)
    int a_addr[8];
#pragma unroll
    for (int ks = 0; ks < 8; ++ks)
        a_addr[ks] = rl * 512 + (((ks * 4 + lhi) ^ rl) * 16);
    int j = jw + p * 16 + l15;
    int row0 = bi * 4;                   // single h copy at row bi*4
    int wofs = (row0 * 256 + (((j >> 3) ^ (row0 & 7)) * 8) + (j & 7)) * 2;
    int b = boff + bi;
    int lbg = b * T * 1536 + j * 2;      // gx: 768-ushort rows (bytes); gates at +0,+512,+1024
    int lbo = b * T * 1024 + j * 2;      // out: 512-bf16 rows (bytes)

    for (int x = tid; x < 2048; x += 512) hbuf[0][x] = 0;
    __syncthreads();

    int voA, voB;

#define GSTEP(RB, WB, TT, VPRE, VCUR)                                             \
    {                                                                             \
        int p_ = (TT);                                                            \
        if (dir) p_ = ((TT) < len) ? (len - 1 - (TT)) : (TT);                     \
        const char* grow = (const char*)gx + (lbg + p_ * 1536);                   \
        ushort rxu = *(const ushort*)grow;                                        \
        ushort zxu = *(const ushort*)(grow + 512);                                \
        ushort nxu = *(const ushort*)(grow + 1024);                               \
        VCUR = lbo + p_ * 1024;                                                   \
        if ((TT) != 0) {                                                          \
            *(ushort*)((char*)outbase + VPRE) = hbf;                              \
        }                                                                         \
        f32x4 acc0 = {0.f,0.f,0.f,0.f}, acc1 = acc0, acc2 = acc0, acc3 = acc0;    \
        f32x4 acc4 = {bhn0, bhn0, bhn0, bhn0};                                    \
        f32x4 acc5 = {bhn1, bhn1, bhn1, bhn1};                                    \
        __builtin_amdgcn_s_setprio(1);                                            \
        _Pragma("unroll")                                                         \
        for (int ks = 0; ks < 8; ++ks) {                                          \
            bf16x8 a = *(const bf16x8*)((const char*)&hbuf[RB][0] + a_addr[ks]);  \
            acc0 = MFMA16(a, B0[ks], acc0, 0, 0, 0);                              \
            acc1 = MFMA16(a, B1[ks], acc1, 0, 0, 0);                              \
            acc2 = MFMA16(a, B2[ks], acc2, 0, 0, 0);                              \
            acc3 = MFMA16(a, B3[ks], acc3, 0, 0, 0);                              \
            acc4 = MFMA16(a, B4[ks], acc4, 0, 0, 0);                              \
            acc5 = MFMA16(a, B5[ks], acc5, 0, 0, 0);                              \
        }                                                                         \
        __builtin_amdgcn_s_setprio(0);                                            \
        {                                                                         \
            float ar = p ? acc1[0] : acc0[0];                                     \
            float az = p ? acc3[0] : acc2[0];                                     \
            float an = p ? acc5[0] : acc4[0];                                     \
            float rx = bf2f(rxu);                                                 \
            float zx = bf2f(zxu);                                                 \
            float nx = bf2f(nxu);                                                 \
            float r = sigf(rx + ar);                                              \
            float z = sigf(zx + az);                                              \
            float nn = tanhf_(nx + r * an);                                       \
            float h = (1.f - z) * nn + z * hp;                                    \
            hp = h;                                                               \
            unsigned pk;                                                          \
            asm("v_cvt_pk_bf16_f32 %0, %1, %2" : "=v"(pk) : "v"(h), "v"(h));      \
            hbf = (ushort)(pk & 0xffffu);                                         \
            *(ushort*)((char*)&hbuf[WB][0] + wofs) = hbf;                         \
        }                                                                         \
        asm volatile("s_waitcnt lgkmcnt(0)" ::: "memory");                        \
        __builtin_amdgcn_s_barrier();                                             \
    }

    for (int t = 0; t < T; t += 2) {
        GSTEP(0, 1, t,     voB, voA)
        GSTEP(1, 0, t + 1, voA, voB)
    }
#undef GSTEP
    *(ushort*)((char*)outbase + voB) = hbf;   // epilogue: h(T-1)
}

// ---------------- MFMA M-GEMM: M[b,d,q] = dos[b,d,:] . qos[b,q,:]  (K=512, bf16 in) ----------------
__global__ __launch_bounds__(256) void k_mgemm(const ushort* __restrict__ dos, const ushort* __restrict__ qos,
                                               float* __restrict__ Mm) {
    __shared__ ushort Asl[64 * 512];   // 64 KB
    __shared__ ushort Bsl[64 * 512];   // 64 KB
    int tid = threadIdx.x;
    int b = blockIdx.y;
    int m0 = blockIdx.x * 64;
    int wv = tid >> 6;
    int lane = tid & 63;
    int l15 = lane & 15;
    int lhi = lane >> 4;

    // ---- stage dos tile + qos (bf16, swizzled chunks, no conversion) ----
    {
        int row = tid >> 2, kq = tid & 3;
        const ushort* ar = dos + ((long)b * DLEN + m0 + row) * 512 + kq * 128;
        const ushort* br = qos + ((long)b * QLEN + row) * 512 + kq * 128;
#pragma unroll
        for (int it = 0; it < 16; ++it) {
            int c = kq * 16 + it;
            int dst = row * 512 + ((c ^ (row & 7)) * 8);
            *(u16x8*)&Asl[dst] = *(const u16x8*)(ar + it * 8);
            *(u16x8*)&Bsl[dst] = *(const u16x8*)(br + it * 8);
        }
    }
    __syncthreads();

    f32x4 acc[4] = {};
#pragma unroll
    for (int ks = 0; ks < 16; ++ks) {
        int arow = wv * 16 + l15;
        bf16x8 a = *(const bf16x8*)&Asl[arow * 512 + (((ks * 4 + lhi) ^ (l15 & 7)) * 8)];
#pragma unroll
        for (int nt = 0; nt < 4; ++nt) {
            int brow = nt * 16 + l15;
            bf16x8 bv = *(const bf16x8*)&Bsl[brow * 512 + (((ks * 4 + lhi) ^ (l15 & 7)) * 8)];
            acc[nt] = MFMA16(a, bv, acc[nt], 0, 0, 0);
        }
    }

#pragma unroll
    for (int nt = 0; nt < 4; ++nt)
#pragma unroll
        for (int i = 0; i < 4; ++i) {
            long m = (long)b * DLEN + m0 + wv * 16 + lhi * 4 + i;
            Mm[m * QLEN + nt * 16 + l15] = acc[nt][i];
        }
}

// ---------------- fused attention epilogue: avgbeta + colstats -> s (LDS) -> final ----------------
__global__ __launch_bounds__(256) void k_aoa(const float* __restrict__ Mm, const float* __restrict__ dmask,
                                             const float* __restrict__ qmask, const int* __restrict__ dlens,
                                             const int* __restrict__ doc, const int* __restrict__ cand,
                                             const int* __restrict__ ans, float* __restrict__ out) {
    int b = blockIdx.x, tid = threadIdx.x;
    int lane = tid & 63, wid = tid >> 6;
    float qm = qmask[b * QLEN + lane];

    float accA = 0.f;
    float mrun = -INFINITY, srun = 0.f;
    for (int d = wid; d < DLEN; d += 4) {
        float x = Mm[((long)b * DLEN + d) * QLEN + lane];
        float dm = dmask[b * DLEN + d];
        float mx = x;
#pragma unroll
        for (int o = 32; o; o >>= 1) mx = fmaxf(mx, __shfl_xor(mx, o));
        float e = expf(x - mx) * dm * qm;
        float sm = e;
#pragma unroll
        for (int o = 32; o; o >>= 1) sm += __shfl_xor(sm, o);
        accA += e / (sm + 1e-12f);
        float mn = fmaxf(mrun, x);
        srun = srun * expf(mrun - mn) + expf(x - mn) * dm;
        mrun = mn;
    }
    __shared__ float redA[4][QLEN], mS[4][QLEN], sS[4][QLEN];
    __shared__ float wq[QLEN], mxs[QLEN];
    __shared__ float sL[DLEN];
    redA[wid][lane] = accA;
    mS[wid][lane] = mrun;
    sS[wid][lane] = srun;
    __syncthreads();
    if (tid < QLEN) {
        float M0 = fmaxf(fmaxf(mS[0][tid], mS[1][tid]), fmaxf(mS[2][tid], mS[3][tid]));
        float S = 0.f;
#pragma unroll
        for (int i = 0; i < 4; ++i) S += sS[i][tid] * expf(mS[i][tid] - M0);
        float avgbv = (redA[0][tid] + redA[1][tid] + redA[2][tid] + redA[3][tid]) / (float)dlens[b];
        wq[tid] = (qm > 0.f) ? (avgbv / (S + 1e-12f)) : 0.f;
        mxs[tid] = M0;
    }
    __syncthreads();

    for (int d = tid; d < DLEN; d += 256) {
        const float* row = Mm + ((long)b * DLEN + d) * QLEN;
        float acc = 0.f;
#pragma unroll
        for (int q = 0; q < QLEN; q += 4) {
            float4 v = *(const float4*)(row + q);
            acc += expf(v.x - mxs[q + 0]) * wq[q + 0];
            acc += expf(v.y - mxs[q + 1]) * wq[q + 1];
            acc += expf(v.z - mxs[q + 2]) * wq[q + 2];
            acc += expf(v.w - mxs[q + 3]) * wq[q + 3];
        }
        sL[d] = dmask[b * DLEN + d] * acc;
    }
    __syncthreads();

    __shared__ int lc[NCAND];
    __shared__ int la;
    __shared__ float red[4][NCAND + 1];
    if (tid < NCAND) lc[tid] = cand[b * NCAND + tid];
    if (tid == NCAND) la = ans[b];
    __syncthreads();
    float accs[NCAND + 1] = {};
    for (int d = tid; d < DLEN; d += 256) {
        int tk = doc[b * DLEN + d];
        float sv = sL[d];
#pragma unroll
        for (int c = 0; c < NCAND; ++c)
            if (tk == lc[c]) accs[c] += sv;
        if (tk == la) accs[NCAND] += sv;
    }
#pragma unroll
    for (int i = 0; i <= NCAND; ++i) {
        float v = accs[i];
#pragma unroll
        for (int o = 32; o; o >>= 1) v += __shfl_xor(v, o);
        if (lane == 0) red[wid][i] = v;
    }
    __syncthreads();
    if (tid == 0) {
        float cp[NCAND + 1];
#pragma unroll
        for (int i = 0; i <= NCAND; ++i) cp[i] = red[0][i] + red[1][i] + red[2][i] + red[3][i];
        int loc = 0; float best = cp[0];
#pragma unroll
        for (int c = 1; c < NCAND; ++c) if (cp[c] > best) { best = cp[c]; loc = c; }
        out[b] = (float)lc[loc];
        out[BATCH + b] = (float)loc;
        out[2 * BATCH + b] = cp[NCAND];
    }
}

__global__ void k_zero_out(float* out, int n) {
    int i = blockIdx.x * 256 + threadIdx.x;
    if (i < n) out[i] = 0.f;
}

extern "C" void kernel_launch(void* const* d_in, const int* in_sizes, int n_in,
                              void* d_out, int out_size, void* d_ws, size_t ws_size,
                              hipStream_t stream) {
    const int*   docs_input   = (const int*)d_in[0];
    const int*   docs_len     = (const int*)d_in[1];
    const float* doc_mask     = (const float*)d_in[2];
    const int*   querys_input = (const int*)d_in[3];
    const int*   querys_len   = (const int*)d_in[4];
    const float* query_mask   = (const float*)d_in[5];
    const int*   candidates   = (const int*)d_in[6];
    const int*   answers      = (const int*)d_in[7];
    const float* embedding    = (const float*)d_in[8];
    const float* w_ih_f = (const float*)d_in[9];
    const float* w_hh_f = (const float*)d_in[10];
    const float* b_ih_f = (const float*)d_in[11];
    const float* b_hh_f = (const float*)d_in[12];
    const float* w_ih_b = (const float*)d_in[13];
    const float* w_hh_b = (const float*)d_in[14];
    const float* b_ih_b = (const float*)d_in[15];
    const float* b_hh_b = (const float*)d_in[16];

    char* ws = (char*)d_ws;
    size_t off = 0;
    auto alloc = [&](size_t bytes) { size_t o = off; off = (off + bytes + 255) & ~(size_t)255; return o; };
    ushort* wprep = (ushort*)(ws + alloc((size_t)2 * 196608 * 2));
    float*  beff  = (float*)(ws + alloc((size_t)2 * G3 * 4));
    ushort* embB  = (ushort*)(ws + alloc((size_t)VOCAB * EMB * 2));
    ushort* wihB  = (ushort*)(ws + alloc((size_t)2 * G3 * EMB * 2));
    ushort* gxq_f = (ushort*)(ws + alloc((size_t)BATCH * QLEN * G3 * 2));
    ushort* gxq_b = (ushort*)(ws + alloc((size_t)BATCH * QLEN * G3 * 2));
    ushort* gxd_f = (ushort*)(ws + alloc((size_t)BATCH * DLEN * G3 * 2));
    ushort* gxd_b = (ushort*)(ws + alloc((size_t)BATCH * DLEN * G3 * 2));
    ushort* dosb  = (ushort*)(ws + alloc((size_t)BATCH * DLEN * 512 * 2));
    ushort* qosb  = (ushort*)(ws + alloc((size_t)BATCH * QLEN * 512 * 2));
    float* Mbuf   = (float*)(ws + alloc((size_t)BATCH * DLEN * QLEN * 4));

    if (ws_size < off) {
        k_zero_out<<<1, 256, 0, stream>>>((float*)d_out, out_size);
        return;
    }

    // fused one-time prep (bf16 conversions + bias folding + w_hh fragments)
    k_prep_all<<<(int)((PREP_TOTAL + 255) / 256), 256, 0, stream>>>(
        embedding, w_ih_f, w_ih_b, b_ih_f, b_hh_f, b_ih_b, b_hh_b, w_hh_f, w_hh_b,
        embB, wihB, beff, wprep);

    // gx for queries and docs, both directions (all-bf16 MFMA, natural coalesced out)
    k_gx<<<dim3(12, (BATCH * QLEN) / 64, 2), 256, 0, stream>>>(querys_input, embB,
        wihB, beff, gxq_f, wihB + (size_t)G3 * EMB, beff + G3, gxq_b);
    k_gx<<<dim3(12, (BATCH * DLEN) / 64, 2), 256, 0, stream>>>(docs_input, embB,
        wihB, beff, gxd_f, wihB + (size_t)G3 * EMB, beff + G3, gxd_b);

    // all four BiGRU scans (doc/query x fwd/bwd), batch split in pairs
    k_gru5<<<64, 512, 0, stream>>>(gxd_f, gxd_b, gxq_f, gxq_b, wprep,
                                   b_hh_f, b_hh_b, docs_len, querys_len, dosb, qosb);

    // attention-over-attention
    k_mgemm<<<dim3(DLEN / 64, BATCH), 256, 0, stream>>>(dosb, qosb, Mbuf);
    k_aoa<<<BATCH, 256, 0, stream>>>(Mbuf, doc_mask, query_mask, docs_len,
                                     docs_input, candidates, answers, (float*)d_out);
}

// Round 22
// 1299.439 us; speedup vs baseline: 1.0296x; 1.0296x over previous
//
#include <hip/hip_runtime.h>
#include <hip/hip_bf16.h>
#include <math.h>

// AoA Reader v17: v15 (r20, __syncthreads GRU) + direction-fused k_gx (8 waves share
// one gathered A-stage). V=50000 E=384 H=256 B=32 D=1024 Q=64 C=10.
#define BATCH 32
#define DLEN 1024
#define QLEN 64
#define EMB 384
#define HID 256
#define G3 768   // 3*H
#define NCAND 10
#define VOCAB 50000

typedef __attribute__((ext_vector_type(8))) short bf16x8;
typedef __attribute__((ext_vector_type(8))) unsigned short u16x8;
typedef __attribute__((ext_vector_type(4))) float f32x4;
#define MFMA16 __builtin_amdgcn_mfma_f32_16x16x32_bf16

__device__ __forceinline__ float bf2f(ushort u) {
    union { float f; unsigned v; } x; x.v = ((unsigned)u) << 16; return x.f;
}
__device__ __forceinline__ ushort f2bf(float f) {
    union { float f; unsigned v; } x; x.f = f;
    unsigned r = x.v + 0x7FFF + ((x.v >> 16) & 1);
    return (ushort)(r >> 16);
}
__device__ __forceinline__ float sigf(float x) {
    return __builtin_amdgcn_rcpf(1.f + __expf(-x));
}
__device__ __forceinline__ float tanhf_(float x) {
    return 1.f - 2.f * __builtin_amdgcn_rcpf(1.f + __expf(2.f * x));
}
__device__ __forceinline__ bf16x8 cvt8(float4 a, float4 b) {
    union { unsigned u[4]; bf16x8 v; } r;
    asm("v_cvt_pk_bf16_f32 %0, %1, %2" : "=v"(r.u[0]) : "v"(a.x), "v"(a.y));
    asm("v_cvt_pk_bf16_f32 %0, %1, %2" : "=v"(r.u[1]) : "v"(a.z), "v"(a.w));
    asm("v_cvt_pk_bf16_f32 %0, %1, %2" : "=v"(r.u[2]) : "v"(b.x), "v"(b.y));
    asm("v_cvt_pk_bf16_f32 %0, %1, %2" : "=v"(r.u[3]) : "v"(b.z), "v"(b.w));
    return r.v;
}

// ---------------- fused prep: embB + wihB(f,b) + bias_eff + wprep in ONE launch ----------------
#define NE8 (VOCAB * EMB / 8)
#define NW8 (G3 * EMB / 8)
__global__ __launch_bounds__(256) void k_prep_all(
    const float* __restrict__ emb, const float* __restrict__ wihf, const float* __restrict__ wihb,
    const float* __restrict__ bihf, const float* __restrict__ bhhf,
    const float* __restrict__ bihb, const float* __restrict__ bhhb,
    const float* __restrict__ whf, const float* __restrict__ whb,
    ushort* __restrict__ embB, ushort* __restrict__ wihB,
    float* __restrict__ be, ushort* __restrict__ wprep)
{
    long i = (long)blockIdx.x * 256 + threadIdx.x;
    if (i < NE8) {
        const float* p = emb + i * 8;
        *(bf16x8*)(embB + i * 8) = cvt8(*(const float4*)p, *(const float4*)(p + 4));
        return;
    }
    i -= NE8;
    if (i < 2 * NW8) {
        const float* w = (i < NW8) ? wihf : wihb;
        long c = (i < NW8) ? i : i - NW8;
        const float* p = w + c * 8;
        *(bf16x8*)(wihB + i * 8) = cvt8(*(const float4*)p, *(const float4*)(p + 4));
        return;
    }
    i -= 2 * NW8;
    if (i < 1536) {
        int dir = (int)i / G3, c = (int)i - dir * G3;
        const float* bih = dir ? bihb : bihf;
        const float* bhh = dir ? bhhb : bhhf;
        be[i] = bih[c] + (c < 512 ? bhh[c] : 0.f);
        return;
    }
    i -= 1536;
    if (i < 393216) {
        int idx = (int)i;
        int dir = idx / 196608;
        int r = idx - dir * 196608;
        int wv = r / 24576;  int r2 = r - wv * 24576;
        int tile = r2 / 4096; int r3 = r2 - tile * 4096;
        int ks = r3 / 512;    int r4 = r3 - ks * 512;
        int lane = r4 >> 3;   int e = r4 & 7;
        int g = (tile >> 1) * 256 + wv * 32 + (tile & 1) * 16 + (lane & 15);
        int k = ks * 32 + (lane >> 4) * 8 + e;
        const float* w = dir ? whb : whf;
        wprep[idx] = f2bf(w[g * 256 + k]);
    }
}
#define PREP_TOTAL ((long)NE8 + 2 * NW8 + 1536 + 393216)

// ---------------- gx GEMM with gather, MFMA bf16, BOTH DIRS FUSED (one A-stage) ----------------
// 512 thr = 8 waves: wave wv -> dir = wv>>2, n-tile = (wv&3)*16. Natural coalesced out.
__global__ __launch_bounds__(512) void k_gx(const int* __restrict__ tokens,
                                            const ushort* __restrict__ embB,
                                            const ushort* __restrict__ wihB,   // [2][G3][EMB]
                                            const float* __restrict__ beff,    // [2][G3]
                                            ushort* __restrict__ out0, ushort* __restrict__ out1) {
    __shared__ ushort Asl[64][392];              // 384 k + 8 pad, 50 KB
    int tid = threadIdx.x;
    int n0 = blockIdx.x * 64;
    long m0 = (long)blockIdx.y * 64;
    int wv = tid >> 6;
    int lane = tid & 63;
    int l15 = lane & 15;
    int lhi = lane >> 4;
    int dir = wv >> 2;

    // ---- stage A once: 8 threads/row, 6 x 16B bf16 loads each ----
    {
        int row = tid >> 3, kq = tid & 7;
        long tok = tokens[m0 + row];
        const ushort* ar = embB + tok * EMB + kq * 48;
#pragma unroll
        for (int it = 0; it < 6; ++it)
            *(u16x8*)&Asl[row][kq * 48 + it * 8] = *(const u16x8*)(ar + it * 8);
    }
    __syncthreads();

    // ---- compute: wave -> (dir, n-tile); 4 m-subtiles ----
    int n = n0 + (wv & 3) * 16 + l15;
    const ushort* brow = wihB + (size_t)dir * G3 * EMB + (long)n * EMB;
    ushort* out = dir ? out1 : out0;
    f32x4 acc[4] = {};
#pragma unroll
    for (int ks = 0; ks < 12; ++ks) {
        bf16x8 bf = *(const bf16x8*)(brow + ks * 32 + lhi * 8);
#pragma unroll
        for (int mt = 0; mt < 4; ++mt) {
            bf16x8 a = *(const bf16x8*)&Asl[mt * 16 + l15][ks * 32 + lhi * 8];
            acc[mt] = MFMA16(a, bf, acc[mt], 0, 0, 0);
        }
    }

    // ---- epilogue: bias + natural bf16 store ----
    float bias = beff[dir * G3 + n];
#pragma unroll
    for (int mt = 0; mt < 4; ++mt)
#pragma unroll
        for (int r = 0; r < 4; ++r) {
            long m = m0 + mt * 16 + lhi * 4 + r;
            out[m * G3 + n] = f2bf(acc[mt][r] + bias);
        }
}

// ---------------- MFMA GRU: grid 64 = (bgroup(16), dir(2), seq(2)). 512 thr = 8 waves. ----------------
// nb=2; batch bi -> A-row bi*4 (row-alias A-read). All 6 B-tiles in registers.
// setprio around MFMA. __syncthreads barrier (v15 best config).
__global__ __attribute__((amdgpu_flat_work_group_size(512, 512), amdgpu_waves_per_eu(2, 2)))
void k_gru5(
    const ushort* __restrict__ gxd_f, const ushort* __restrict__ gxd_b,
    const ushort* __restrict__ gxq_f, const ushort* __restrict__ gxq_b,
    const ushort* __restrict__ wprep,
    const float* __restrict__ bhh_f, const float* __restrict__ bhh_b,
    const int* __restrict__ dlens, const int* __restrict__ qlens,
    ushort* __restrict__ dosb, ushort* __restrict__ qosb)
{
    int wg = blockIdx.x;
    int bgroup = wg & 15;
    int dir = (wg >> 4) & 1;
    int seq = wg >> 5;                   // 0=doc, 1=query
    int T = seq ? QLEN : DLEN;
    const ushort* gx = seq ? (dir ? gxq_b : gxq_f) : (dir ? gxd_b : gxd_f);
    const float* bhh = dir ? bhh_b : bhh_f;
    const int* lens = seq ? qlens : dlens;
    ushort* outbase = (seq ? qosb : dosb) + dir * HID;
    int boff = bgroup * 2;

    int tid = threadIdx.x;
    int wv = tid >> 6;
    int lane = tid & 63;
    int l15 = lane & 15;
    int lhi = lane >> 4;
    int bi = lhi & 1;                    // local batch
    int p  = lhi >> 1;                   // j-half
    int jw = wv * 32;

    __shared__ ushort hbuf[2][2048];     // 8 KB bf16 h (8 rows), swizzled, dbuf

    // ---- resident weights: ALL 6 tiles in registers ----
    const ushort* wp = wprep + (size_t)dir * 196608;
    bf16x8 B0[8], B1[8], B2[8], B3[8], B4[8], B5[8];
#pragma unroll
    for (int ks = 0; ks < 8; ++ks) {
        B0[ks] = *(const bf16x8*)(wp + ((((wv * 6 + 0) * 8 + ks) * 64 + lane) * 8));
        B1[ks] = *(const bf16x8*)(wp + ((((wv * 6 + 1) * 8 + ks) * 64 + lane) * 8));
        B2[ks] = *(const bf16x8*)(wp + ((((wv * 6 + 2) * 8 + ks) * 64 + lane) * 8));
        B3[ks] = *(const bf16x8*)(wp + ((((wv * 6 + 3) * 8 + ks) * 64 + lane) * 8));
        B4[ks] = *(const bf16x8*)(wp + ((((wv * 6 + 4) * 8 + ks) * 64 + lane) * 8));
        B5[ks] = *(const bf16x8*)(wp + ((((wv * 6 + 5) * 8 + ks) * 64 + lane) * 8));
    }

    float bhn0 = bhh[512 + jw + l15];
    float bhn1 = bhh[512 + jw + 16 + l15];
    int len = lens[boff + bi];
    float hp = 0.f;
    ushort hbf = 0;

    // ---- precomputed static addresses (t-invariant) ----
    int rl = l15 & 7;                    // aliased A-row (8..15 -> 0..7, same data)
    int a_addr[8];
#pragma unroll
    for (int ks = 0; ks < 8; ++ks)
        a_addr[ks] = rl * 512 + (((ks * 4 + lhi) ^ rl) * 16);
    int j = jw + p * 16 + l15;
    int row0 = bi * 4;                   // single h copy at row bi*4
    int wofs = (row0 * 256 + (((j >> 3) ^ (row0 & 7)) * 8) + (j & 7)) * 2;
    int b = boff + bi;
    int lbg = b * T * 1536 + j * 2;      // gx: 768-ushort rows (bytes); gates at +0,+512,+1024
    int lbo = b * T * 1024 + j * 2;      // out: 512-bf16 rows (bytes)

    for (int x = tid; x < 2048; x += 512) hbuf[0][x] = 0;
    __syncthreads();

    int voA, voB;

#define GSTEP(RB, WB, TT, VPRE, VCUR)                                             \
    {                                                                             \
        int p_ = (TT);                                                            \
        if (dir) p_ = ((TT) < len) ? (len - 1 - (TT)) : (TT);                     \
        const char* grow = (const char*)gx + (lbg + p_ * 1536);                   \
        ushort rxu = *(const ushort*)grow;                                        \
        ushort zxu = *(const ushort*)(grow + 512);                                \
        ushort nxu = *(const ushort*)(grow + 1024);                               \
        VCUR = lbo + p_ * 1024;                                                   \
        if ((TT) != 0) {                                                          \
            *(ushort*)((char*)outbase + VPRE) = hbf;                              \
        }                                                                         \
        f32x4 acc0 = {0.f,0.f,0.f,0.f}, acc1 = acc0, acc2 = acc0, acc3 = acc0;    \
        f32x4 acc4 = {bhn0, bhn0, bhn0, bhn0};                                    \
        f32x4 acc5 = {bhn1, bhn1, bhn1, bhn1};                                    \
        __builtin_amdgcn_s_setprio(1);                                            \
        _Pragma("unroll")                                                         \
        for (int ks = 0; ks < 8; ++ks) {                                          \
            bf16x8 a = *(const bf16x8*)((const char*)&hbuf[RB][0] + a_addr[ks]);  \
            acc0 = MFMA16(a, B0[ks], acc0, 0, 0, 0);                              \
            acc1 = MFMA16(a, B1[ks], acc1, 0, 0, 0);                              \
            acc2 = MFMA16(a, B2[ks], acc2, 0, 0, 0);                              \
            acc3 = MFMA16(a, B3[ks], acc3, 0, 0, 0);                              \
            acc4 = MFMA16(a, B4[ks], acc4, 0, 0, 0);                              \
            acc5 = MFMA16(a, B5[ks], acc5, 0, 0, 0);                              \
        }                                                                         \
        __builtin_amdgcn_s_setprio(0);                                            \
        {                                                                         \
            float ar = p ? acc1[0] : acc0[0];                                     \
            float az = p ? acc3[0] : acc2[0];                                     \
            float an = p ? acc5[0] : acc4[0];                                     \
            float rx = bf2f(rxu);                                                 \
            float zx = bf2f(zxu);                                                 \
            float nx = bf2f(nxu);                                                 \
            float r = sigf(rx + ar);                                              \
            float z = sigf(zx + az);                                              \
            float nn = tanhf_(nx + r * an);                                       \
            float h = (1.f - z) * nn + z * hp;                                    \
            hp = h;                                                               \
            unsigned pk;                                                          \
            asm("v_cvt_pk_bf16_f32 %0, %1, %2" : "=v"(pk) : "v"(h), "v"(h));      \
            hbf = (ushort)(pk & 0xffffu);                                         \
            *(ushort*)((char*)&hbuf[WB][0] + wofs) = hbf;                         \
        }                                                                         \
        __syncthreads();                                                          \
    }

    for (int t = 0; t < T; t += 2) {
        GSTEP(0, 1, t,     voB, voA)
        GSTEP(1, 0, t + 1, voA, voB)
    }
#undef GSTEP
    *(ushort*)((char*)outbase + voB) = hbf;   // epilogue: h(T-1)
}

// ---------------- MFMA M-GEMM: M[b,d,q] = dos[b,d,:] . qos[b,q,:]  (K=512, bf16 in) ----------------
__global__ __launch_bounds__(256) void k_mgemm(const ushort* __restrict__ dos, const ushort* __restrict__ qos,
                                               float* __restrict__ Mm) {
    __shared__ ushort Asl[64 * 512];   // 64 KB
    __shared__ ushort Bsl[64 * 512];   // 64 KB
    int tid = threadIdx.x;
    int b = blockIdx.y;
    int m0 = blockIdx.x * 64;
    int wv = tid >> 6;
    int lane = tid & 63;
    int l15 = lane & 15;
    int lhi = lane >> 4;

    // ---- stage dos tile + qos (bf16, swizzled chunks, no conversion) ----
    {
        int row = tid >> 2, kq = tid & 3;
        const ushort* ar = dos + ((long)b * DLEN + m0 + row) * 512 + kq * 128;
        const ushort* br = qos + ((long)b * QLEN + row) * 512 + kq * 128;
#pragma unroll
        for (int it = 0; it < 16; ++it) {
            int c = kq * 16 + it;
            int dst = row * 512 + ((c ^ (row & 7)) * 8);
            *(u16x8*)&Asl[dst] = *(const u16x8*)(ar + it * 8);
            *(u16x8*)&Bsl[dst] = *(const u16x8*)(br + it * 8);
        }
    }
    __syncthreads();

    f32x4 acc[4] = {};
#pragma unroll
    for (int ks = 0; ks < 16; ++ks) {
        int arow = wv * 16 + l15;
        bf16x8 a = *(const bf16x8*)&Asl[arow * 512 + (((ks * 4 + lhi) ^ (l15 & 7)) * 8)];
#pragma unroll
        for (int nt = 0; nt < 4; ++nt) {
            int brow = nt * 16 + l15;
            bf16x8 bv = *(const bf16x8*)&Bsl[brow * 512 + (((ks * 4 + lhi) ^ (l15 & 7)) * 8)];
            acc[nt] = MFMA16(a, bv, acc[nt], 0, 0, 0);
        }
    }

#pragma unroll
    for (int nt = 0; nt < 4; ++nt)
#pragma unroll
        for (int i = 0; i < 4; ++i) {
            long m = (long)b * DLEN + m0 + wv * 16 + lhi * 4 + i;
            Mm[m * QLEN + nt * 16 + l15] = acc[nt][i];
        }
}

// ---------------- fused attention epilogue: avgbeta + colstats -> s (LDS) -> final ----------------
__global__ __launch_bounds__(256) void k_aoa(const float* __restrict__ Mm, const float* __restrict__ dmask,
                                             const float* __restrict__ qmask, const int* __restrict__ dlens,
                                             const int* __restrict__ doc, const int* __restrict__ cand,
                                             const int* __restrict__ ans, float* __restrict__ out) {
    int b = blockIdx.x, tid = threadIdx.x;
    int lane = tid & 63, wid = tid >> 6;
    float qm = qmask[b * QLEN + lane];

    float accA = 0.f;
    float mrun = -INFINITY, srun = 0.f;
    for (int d = wid; d < DLEN; d += 4) {
        float x = Mm[((long)b * DLEN + d) * QLEN + lane];
        float dm = dmask[b * DLEN + d];
        float mx = x;
#pragma unroll
        for (int o = 32; o; o >>= 1) mx = fmaxf(mx, __shfl_xor(mx, o));
        float e = expf(x - mx) * dm * qm;
        float sm = e;
#pragma unroll
        for (int o = 32; o; o >>= 1) sm += __shfl_xor(sm, o);
        accA += e / (sm + 1e-12f);
        float mn = fmaxf(mrun, x);
        srun = srun * expf(mrun - mn) + expf(x - mn) * dm;
        mrun = mn;
    }
    __shared__ float redA[4][QLEN], mS[4][QLEN], sS[4][QLEN];
    __shared__ float wq[QLEN], mxs[QLEN];
    __shared__ float sL[DLEN];
    redA[wid][lane] = accA;
    mS[wid][lane] = mrun;
    sS[wid][lane] = srun;
    __syncthreads();
    if (tid < QLEN) {
        float M0 = fmaxf(fmaxf(mS[0][tid], mS[1][tid]), fmaxf(mS[2][tid], mS[3][tid]));
        float S = 0.f;
#pragma unroll
        for (int i = 0; i < 4; ++i) S += sS[i][tid] * expf(mS[i][tid] - M0);
        float avgbv = (redA[0][tid] + redA[1][tid] + redA[2][tid] + redA[3][tid]) / (float)dlens[b];
        wq[tid] = (qm > 0.f) ? (avgbv / (S + 1e-12f)) : 0.f;
        mxs[tid] = M0;
    }
    __syncthreads();

    for (int d = tid; d < DLEN; d += 256) {
        const float* row = Mm + ((long)b * DLEN + d) * QLEN;
        float acc = 0.f;
#pragma unroll
        for (int q = 0; q < QLEN; q += 4) {
            float4 v = *(const float4*)(row + q);
            acc += expf(v.x - mxs[q + 0]) * wq[q + 0];
            acc += expf(v.y - mxs[q + 1]) * wq[q + 1];
            acc += expf(v.z - mxs[q + 2]) * wq[q + 2];
            acc += expf(v.w - mxs[q + 3]) * wq[q + 3];
        }
        sL[d] = dmask[b * DLEN + d] * acc;
    }
    __syncthreads();

    __shared__ int lc[NCAND];
    __shared__ int la;
    __shared__ float red[4][NCAND + 1];
    if (tid < NCAND) lc[tid] = cand[b * NCAND + tid];
    if (tid == NCAND) la = ans[b];
    __syncthreads();
    float accs[NCAND + 1] = {};
    for (int d = tid; d < DLEN; d += 256) {
        int tk = doc[b * DLEN + d];
        float sv = sL[d];
#pragma unroll
        for (int c = 0; c < NCAND; ++c)
            if (tk == lc[c]) accs[c] += sv;
        if (tk == la) accs[NCAND] += sv;
    }
#pragma unroll
    for (int i = 0; i <= NCAND; ++i) {
        float v = accs[i];
#pragma unroll
        for (int o = 32; o; o >>= 1) v += __shfl_xor(v, o);
        if (lane == 0) red[wid][i] = v;
    }
    __syncthreads();
    if (tid == 0) {
        float cp[NCAND + 1];
#pragma unroll
        for (int i = 0; i <= NCAND; ++i) cp[i] = red[0][i] + red[1][i] + red[2][i] + red[3][i];
        int loc = 0; float best = cp[0];
#pragma unroll
        for (int c = 1; c < NCAND; ++c) if (cp[c] > best) { best = cp[c]; loc = c; }
        out[b] = (float)lc[loc];
        out[BATCH + b] = (float)loc;
        out[2 * BATCH + b] = cp[NCAND];
    }
}

__global__ void k_zero_out(float* out, int n) {
    int i = blockIdx.x * 256 + threadIdx.x;
    if (i < n) out[i] = 0.f;
}

extern "C" void kernel_launch(void* const* d_in, const int* in_sizes, int n_in,
                              void* d_out, int out_size, void* d_ws, size_t ws_size,
                              hipStream_t stream) {
    const int*   docs_input   = (const int*)d_in[0];
    const int*   docs_len     = (const int*)d_in[1];
    const float* doc_mask     = (const float*)d_in[2];
    const int*   querys_input = (const int*)d_in[3];
    const int*   querys_len   = (const int*)d_in[4];
    const float* query_mask   = (const float*)d_in[5];
    const int*   candidates   = (const int*)d_in[6];
    const int*   answers      = (const int*)d_in[7];
    const float* embedding    = (const float*)d_in[8];
    const float* w_ih_f = (const float*)d_in[9];
    const float* w_hh_f = (const float*)d_in[10];
    const float* b_ih_f = (const float*)d_in[11];
    const float* b_hh_f = (const float*)d_in[12];
    const float* w_ih_b = (const float*)d_in[13];
    const float* w_hh_b = (const float*)d_in[14];
    const float* b_ih_b = (const float*)d_in[15];
    const float* b_hh_b = (const float*)d_in[16];

    char* ws = (char*)d_ws;
    size_t off = 0;
    auto alloc = [&](size_t bytes) { size_t o = off; off = (off + bytes + 255) & ~(size_t)255; return o; };
    ushort* wprep = (ushort*)(ws + alloc((size_t)2 * 196608 * 2));
    float*  beff  = (float*)(ws + alloc((size_t)2 * G3 * 4));
    ushort* embB  = (ushort*)(ws + alloc((size_t)VOCAB * EMB * 2));
    ushort* wihB  = (ushort*)(ws + alloc((size_t)2 * G3 * EMB * 2));
    ushort* gxq_f = (ushort*)(ws + alloc((size_t)BATCH * QLEN * G3 * 2));
    ushort* gxq_b = (ushort*)(ws + alloc((size_t)BATCH * QLEN * G3 * 2));
    ushort* gxd_f = (ushort*)(ws + alloc((size_t)BATCH * DLEN * G3 * 2));
    ushort* gxd_b = (ushort*)(ws + alloc((size_t)BATCH * DLEN * G3 * 2));
    ushort* dosb  = (ushort*)(ws + alloc((size_t)BATCH * DLEN * 512 * 2));
    ushort* qosb  = (ushort*)(ws + alloc((size_t)BATCH * QLEN * 512 * 2));
    float* Mbuf   = (float*)(ws + alloc((size_t)BATCH * DLEN * QLEN * 4));

    if (ws_size < off) {
        k_zero_out<<<1, 256, 0, stream>>>((float*)d_out, out_size);
        return;
    }

    // fused one-time prep (bf16 conversions + bias folding + w_hh fragments)
    k_prep_all<<<(int)((PREP_TOTAL + 255) / 256), 256, 0, stream>>>(
        embedding, w_ih_f, w_ih_b, b_ih_f, b_hh_f, b_ih_b, b_hh_b, w_hh_f, w_hh_b,
        embB, wihB, beff, wprep);

    // gx for queries and docs, BOTH directions fused (one A-stage per tile)
    k_gx<<<dim3(12, (BATCH * QLEN) / 64), 512, 0, stream>>>(querys_input, embB,
        wihB, beff, gxq_f, gxq_b);
    k_gx<<<dim3(12, (BATCH * DLEN) / 64), 512, 0, stream>>>(docs_input, embB,
        wihB, beff, gxd_f, gxd_b);

    // all four BiGRU scans (doc/query x fwd/bwd), batch split in pairs
    k_gru5<<<64, 512, 0, stream>>>(gxd_f, gxd_b, gxq_f, gxq_b, wprep,
                                   b_hh_f, b_hh_b, docs_len, querys_len, dosb, qosb);

    // attention-over-attention
    k_mgemm<<<dim3(DLEN / 64, BATCH), 256, 0, stream>>>(dosb, qosb, Mbuf);
    k_aoa<<<BATCH, 256, 0, stream>>>(Mbuf, doc_mask, query_mask, docs_len,
                                     docs_input, candidates, answers, (float*)d_out);
}